// Round 5
// baseline (164.496 us; speedup 1.0000x reference)
//
#include <hip/hip_runtime.h>
#include <hip/hip_bf16.h>

// Problem constants (fixed by reference). ALL float tensors are float32;
// indices int32. MFMA runs on bf16-converted fragments; accumulate + epilogue
// in fp32.
#define NB     131072   // batch
#define NCH    16       // charts
#define NPAIR  256      // (src,tgt) pair buckets
#define LDW    136      // r4-path LDS weight-row stride (bf16 elems)
#define LDH    136      // r4-path LDS h-row stride
#define CAP    1024     // r4-path sorted-slice chunk capacity

// Workspace layout (ints): hist/cursor @0 (256) | off @256 (257) | sorted @528 (NB)
// | bf16 pre-swizzled weights @131600 (1 MB: enc 512KB then dec 512KB)
#define WS_HIST   0
#define WS_OFF    256
#define WS_SORTED 528
#define WS_WBF    131600                               // int index; byte 526,400 (16B aligned)
#define WS_BYTES  ((WS_SORTED + NB) * 4)               // 526,400 (r4 path)
#define WS_FULL   (WS_BYTES + 2 * 16 * 16384 * 2)      // 1,574,976 (new path)

typedef short short8 __attribute__((ext_vector_type(8)));   // 8 x bf16 (4 VGPRs) MFMA frag
typedef float f32x4  __attribute__((ext_vector_type(4)));   // MFMA accumulator / fp32 vec

__device__ __forceinline__ short bfbits(float x) {
    union { __hip_bfloat16 h; short s; } u;
    u.h = __float2bfloat16(x);
    return u.s;
}

// Load 8 consecutive fp32 (32B, 16B-aligned) and convert to a bf16x8 MFMA frag.
__device__ __forceinline__ short8 cvt_frag(const float* __restrict__ p) {
    const f32x4 lo = *(const f32x4*)p;
    const f32x4 hi = *(const f32x4*)(p + 4);
    short8 r;
    r[0] = bfbits(lo[0]); r[1] = bfbits(lo[1]); r[2] = bfbits(lo[2]); r[3] = bfbits(lo[3]);
    r[4] = bfbits(hi[0]); r[5] = bfbits(hi[1]); r[6] = bfbits(hi[2]); r[7] = bfbits(hi[3]);
    return r;
}

// Pack two f32x4 into one bf16x8 MFMA frag.
__device__ __forceinline__ short8 pack_frag(f32x4 lo, f32x4 hi) {
    short8 r;
    r[0] = bfbits(lo[0]); r[1] = bfbits(lo[1]); r[2] = bfbits(lo[2]); r[3] = bfbits(lo[3]);
    r[4] = bfbits(hi[0]); r[5] = bfbits(hi[1]); r[6] = bfbits(hi[2]); r[7] = bfbits(hi[3]);
    return r;
}

// Async global->LDS DMA, 16B per lane, LDS dest = wave-uniform base + lane*16.
__device__ __forceinline__ void gload_lds16(const void* g, void* l) {
    __builtin_amdgcn_global_load_lds(
        (const __attribute__((address_space(1))) void*)g,
        (__attribute__((address_space(3))) void*)l, 16, 0, 0);
}

// ----------------------------------------------------------------- k_pre ----
// Blocks 0..127: pair histogram (1024 rows each). Blocks 128..191: convert
// fp32 weights -> bf16 into workspace in PRE-SWIZZLED LDS-image layout:
//   img(row, col) = W(row, col ^ ((row&7)<<3))        [short indices]
// so k_gemm2 can global_load_lds the image LINEARLY and read with the same
// XOR -> bank-conflict-free ds_read_b128 (rule: swizzle both sides or neither).
__global__ __launch_bounds__(256) void k_pre(const int* __restrict__ si,
                                             const int* __restrict__ ti,
                                             int* __restrict__ hist,
                                             const float* __restrict__ encw,
                                             const float* __restrict__ decw,
                                             short* __restrict__ wbf) {
    __shared__ int sh[NPAIR];
    const int bid = blockIdx.x;
    const int t = threadIdx.x;
    if (bid < 128) {
        sh[t] = 0;
        __syncthreads();
        const int base = bid * 1024 + t;
#pragma unroll
        for (int j = 0; j < 4; ++j) {
            const int i = base + j * 256;                       // coalesced
            const int k = (si[i] * NCH + ti[i]) & (NPAIR - 1);  // masked: never OOB
            atomicAdd(&sh[k], 1);
        }
        __syncthreads();
        if (sh[t]) atomicAdd(&hist[t], sh[t]);
    } else {
        // 65536 granules of 8 shorts: G = [mat:1][chart:4][row:7][gran:4]
#pragma unroll
        for (int j = 0; j < 4; ++j) {
            const int G   = (bid - 128) * 1024 + j * 256 + t;
            const int gi  = G & 15;
            const int row = (G >> 4) & 127;
            const int ch  = (G >> 11) & 15;
            const int mat = G >> 15;
            const float* src = (mat ? decw : encw) + ch * 16384 + row * 128
                             + ((gi ^ (row & 7)) << 3);          // inverse == same XOR
            short* dst = wbf + mat * 262144 + ch * 16384 + row * 128 + (gi << 3);
            *(short8*)dst = cvt_frag(src);
        }
    }
}

// ---------------------------------------------------------------- k_scan ----
__global__ __launch_bounds__(256) void k_scan(int* __restrict__ hist,
                                              int* __restrict__ off) {
    __shared__ int s[NPAIR];
    const int t = threadIdx.x;
    const int v = hist[t];
    s[t] = v;
    __syncthreads();
#pragma unroll
    for (int d = 1; d < NPAIR; d <<= 1) {
        const int x = (t >= d) ? s[t - d] : 0;
        __syncthreads();
        s[t] += x;
        __syncthreads();
    }
    off[t + 1] = s[t];                 // inclusive -> off[1..256]
    if (t == 0) off[0] = 0;
    hist[t] = s[t] - v;                // exclusive prefix -> cursor start
}

// ------------------------------------------------------------- k_scatter ----
__global__ __launch_bounds__(256) void k_scatter(const int* __restrict__ si,
                                                 const int* __restrict__ ti,
                                                 int* __restrict__ cursor,
                                                 int* __restrict__ sorted) {
    __shared__ int sh[NPAIR];
    __shared__ int sbase[NPAIR];
    const int t = threadIdx.x;
    sh[t] = 0;
    __syncthreads();
    int key[4], rank[4];
    const int base = blockIdx.x * 1024 + t;
#pragma unroll
    for (int j = 0; j < 4; ++j) {
        const int i = base + j * 256;
        const int k = (si[i] * NCH + ti[i]) & (NPAIR - 1);
        key[j]  = k;
        rank[j] = atomicAdd(&sh[k], 1);
    }
    __syncthreads();
    sbase[t] = sh[t] ? atomicAdd(&cursor[t], sh[t]) : 0;
    __syncthreads();
#pragma unroll
    for (int j = 0; j < 4; ++j) {
        const int slot = sbase[key[j]] + rank[j];
        if (slot >= 0 && slot < NB)
            sorted[slot] = base + j * 256;
    }
}

// --------------------------------------------------------------- k_gemm2 ----
// TWO BLOCKS PER BUCKET (grid 512 = 2 blocks/CU co-resident), 256 threads =
// 4 waves, wave-autonomous (zero main-loop barriers). vs round-4:
//  - weights staged via async global_load_lds from the pre-swizzled bf16
//    image (no cvt VALU, no VGPR roundtrip, half the bytes, L2-hot),
//  - LDS = 64KB weights + 16KB h = EXACTLY 80KB -> 2 blocks/CU; the two
//    co-resident blocks drift to different phases so one block's gather/
//    store latency hides under the other's compute,
//  - row indices read straight from `sorted` (64B broadcast line) + width-16
//    shuffles for store rows: no sRowLds, no chunk barriers at all.
// XOR swizzle keeps all ds_read_b128 at worst 2-way (free).
__global__ __launch_bounds__(256, 2)
void k_gemm2(const float* __restrict__ z,
             const short* __restrict__ wbf,
             const float* __restrict__ cpar,
             const float* __restrict__ dpar,
             const int* __restrict__ off,
             const int* __restrict__ sorted,
             float* __restrict__ out) {
    __shared__ __align__(16) short sW1[16384];     // 32,768 B  (128x128, swizzled image)
    __shared__ __align__(16) short sW2[16384];     // 32,768 B
    __shared__ __align__(16) short sH[4 * 2048];   // 16,384 B  (per-wave 16x128 slices)

    const int bucket = blockIdx.x >> 1;
    const int half   = blockIdx.x & 1;
    const int srcc = bucket >> 4;
    const int tgtc = bucket & (NCH - 1);
    const int beg = off[bucket];
    const int end = off[bucket + 1];

    const int tid  = threadIdx.x;
    const int lane = tid & 63;
    const int wv   = tid >> 6;                  // 0..3
    const int lr   = lane & 15;                 // A: m / B: n within tile
    const int lhi  = lane >> 4;                 // k-chunk selector (8 elems each)
    const int swz  = (lr & 7) << 3;             // short-index XOR for row==lr-style reads

    // ---- async DMA: pre-swizzled bf16 weights -> LDS (linear), 1KB/instr ----
    {
        const short* w1 = wbf + srcc * 16384;
        const short* w2 = wbf + 262144 + tgtc * 16384;
#pragma unroll
        for (int i = 0; i < 8; ++i) {
            const int o = (wv * 8 + i) * 512;            // shorts (1KB chunks)
            gload_lds16(w1 + o + lane * 8, sW1 + o);
            gload_lds16(w2 + o + lane * 8, sW2 + o);
        }
    }

    float cb[8], db[8];
#pragma unroll
    for (int nt = 0; nt < 8; ++nt) {
        cb[nt] = cpar[srcc * 128 + nt * 16 + lr];
        db[nt] = dpar[tgtc * 128 + nt * 16 + lr];
    }

    short* const hs = sH + wv * 2048;           // this wave's 16x128 h slice
    const int slot = half * 4 + wv;             // 0..7 across the bucket's 2 blocks
    const int ng   = (end - beg + 15) >> 4;     // 16-row groups in bucket

    f32x4 buf[8];
    int g = slot;
    int rIdx = -1;
    if (g < ng) {                               // first gather, overlapped with DMA
        const int idx = beg + (g << 4) + lr;
        int v = (idx < end) ? sorted[idx] : -1;
        rIdx = ((unsigned)v < (unsigned)NB) ? v : -1;    // clamp: poison -> pad
        const float* p = z + (long)(rIdx < 0 ? 0 : rIdx) * 128 + lhi * 8;
#pragma unroll
        for (int k = 0; k < 4; ++k) {
            buf[2 * k]     = *(const f32x4*)(p + k * 32);
            buf[2 * k + 1] = *(const f32x4*)(p + k * 32 + 4);
        }
    }
    __syncthreads();                            // weights (and first z) resident

    while (g < ng) {
        short8 a[4];
#pragma unroll
        for (int k = 0; k < 4; ++k) a[k] = pack_frag(buf[2 * k], buf[2 * k + 1]);
        const int rCur = rIdx;
        const int gn = g + 8;
        int rN = -1;
        if (gn < ng) {                          // next row indices (L2-hot, hidden)
            const int idx = beg + (gn << 4) + lr;
            int v = (idx < end) ? sorted[idx] : -1;
            rN = ((unsigned)v < (unsigned)NB) ? v : -1;
        }

        // -------- GEMM1: A = z (regs), B = sW1 (swizzled reads, 2-way max) ----
        f32x4 acc[8];
#pragma unroll
        for (int nt = 0; nt < 8; ++nt) acc[nt] = (f32x4)(0.0f);
#pragma unroll
        for (int k = 0; k < 4; ++k) {
            const int kc = k * 32 + lhi * 8;
#pragma unroll
            for (int nt = 0; nt < 8; ++nt) {
                const short8 b = *(const short8*)(sW1 + (nt * 16 + lr) * 128 + (kc ^ swz));
                acc[nt] = __builtin_amdgcn_mfma_f32_16x16x32_bf16(a[k], b, acc[nt], 0, 0, 0);
            }
        }

        if (gn < ng) {                          // next z gather in flight during h+GEMM2
            const float* p = z + (long)(rN < 0 ? 0 : rN) * 128 + lhi * 8;
#pragma unroll
            for (int k = 0; k < 4; ++k) {
                buf[2 * k]     = *(const f32x4*)(p + k * 32);
                buf[2 * k + 1] = *(const f32x4*)(p + k * 32 + 4);
            }
        }

        // h (+ c bias) -> per-wave LDS slice, swizzled; same-wave DS ops are
        // in-order and the compiler orders the aliasing write->read: no barrier.
#pragma unroll
        for (int nt = 0; nt < 8; ++nt)
#pragma unroll
            for (int r = 0; r < 4; ++r) {
                const int row = lhi * 4 + r;
                hs[row * 128 + ((nt * 16 + lr) ^ ((row & 7) << 3))] =
                    bfbits(acc[nt][r] + cb[nt]);
            }

        // -------- GEMM2: A = h (own slice), B = sW2 --------
#pragma unroll
        for (int nt = 0; nt < 8; ++nt) acc[nt] = (f32x4)(0.0f);
#pragma unroll
        for (int k = 0; k < 4; ++k) {
            const int kc = k * 32 + lhi * 8;
            const short8 ah = *(const short8*)(hs + lr * 128 + (kc ^ swz));
#pragma unroll
            for (int nt = 0; nt < 8; ++nt) {
                const short8 b = *(const short8*)(sW2 + (nt * 16 + lr) * 128 + (kc ^ swz));
                acc[nt] = __builtin_amdgcn_mfma_f32_16x16x32_bf16(ah, b, acc[nt], 0, 0, 0);
            }
        }

        // direct stores (+ d bias): per (nt,r) 16 lanes write 64B contiguous;
        // store rows come from width-16 shuffles of this group's row indices.
        int grow[4];
#pragma unroll
        for (int r = 0; r < 4; ++r) grow[r] = __shfl(rCur, lhi * 4 + r, 16);
#pragma unroll
        for (int nt = 0; nt < 8; ++nt)
#pragma unroll
            for (int r = 0; r < 4; ++r)
                if (grow[r] >= 0)
                    out[(long)grow[r] * 128 + nt * 16 + lr] = acc[nt][r] + db[nt];

        rIdx = rN;
        g = gn;
    }
}

// =========================================================================
// Round-4 path (proven, 145.4us): used when workspace can't hold the 1MB
// bf16 weight image. Kernels below are unchanged from round 4.
// =========================================================================
__global__ void k_init(int* __restrict__ hist) {
    hist[threadIdx.x] = 0;
}

__global__ __launch_bounds__(256) void k_hist(const int* __restrict__ si,
                                              const int* __restrict__ ti,
                                              int* __restrict__ hist) {
    __shared__ int sh[NPAIR];
    const int t = threadIdx.x;
    sh[t] = 0;
    __syncthreads();
    const int base = blockIdx.x * 1024 + t;
#pragma unroll
    for (int j = 0; j < 4; ++j) {
        const int i = base + j * 256;
        const int k = (si[i] * NCH + ti[i]) & (NPAIR - 1);
        atomicAdd(&sh[k], 1);
    }
    __syncthreads();
    if (sh[t]) atomicAdd(&hist[t], sh[t]);
}

__global__ __launch_bounds__(512, 2)
void k_gemm(const float* __restrict__ z,
            const float* __restrict__ encw,
            const float* __restrict__ decw,
            const float* __restrict__ cpar,
            const float* __restrict__ dpar,
            const int* __restrict__ off,
            const int* __restrict__ sorted,
            float* __restrict__ out) {
    __shared__ int sRowLds[CAP];
    __shared__ __align__(16) __hip_bfloat16 sW1[128 * LDW];
    __shared__ __align__(16) __hip_bfloat16 sW2[128 * LDW];
    __shared__ __align__(16) __hip_bfloat16 sH[8 * 32 * LDH];

    const int bucket = blockIdx.x;
    const int srcc = bucket >> 4;
    const int tgtc = bucket & (NCH - 1);
    const int beg = off[bucket];
    const int end = off[bucket + 1];

    const int tid  = threadIdx.x;
    const int lane = tid & 63;
    const int wv   = tid >> 6;
    const int lr   = lane & 15;
    const int lhi  = lane >> 4;

    {
        const float* W1 = encw + srcc * 16384;
        const float* W2 = decw + tgtc * 16384;
#pragma unroll
        for (int it = 0; it < 4; ++it) {
            const int f = (it * 512 + tid) * 8;
            const int row = f >> 7, col = f & 127;
            *(short8*)(sW1 + row * LDW + col) = cvt_frag(W1 + f);
            *(short8*)(sW2 + row * LDW + col) = cvt_frag(W2 + f);
        }
    }

    float cb[8], db[8];
#pragma unroll
    for (int nt = 0; nt < 8; ++nt) {
        cb[nt] = cpar[srcc * 128 + nt * 16 + lr];
        db[nt] = dpar[tgtc * 128 + nt * 16 + lr];
    }

    __hip_bfloat16* const hs = sH + wv * (32 * LDH);
    f32x4 bufA[8], bufB[8];

    auto pf = [&](int g) {
        const int r0 = sRowLds[(g << 5) + lr];
        const int r1 = sRowLds[(g << 5) + 16 + lr];
        const float* p0 = z + (long)(r0 < 0 ? 0 : r0) * 128 + lhi * 8;
        const float* p1 = z + (long)(r1 < 0 ? 0 : r1) * 128 + lhi * 8;
#pragma unroll
        for (int k = 0; k < 4; ++k) {
            bufA[2 * k]     = *(const f32x4*)(p0 + k * 32);
            bufA[2 * k + 1] = *(const f32x4*)(p0 + k * 32 + 4);
            bufB[2 * k]     = *(const f32x4*)(p1 + k * 32);
            bufB[2 * k + 1] = *(const f32x4*)(p1 + k * 32 + 4);
        }
    };

    for (int cb0 = beg; cb0 < end; cb0 += CAP) {
        const int cnt = min(end - cb0, CAP);
        __syncthreads();
        for (int i = tid; i < CAP; i += 512) {
            int v = (i < cnt) ? sorted[cb0 + i] : -1;
            sRowLds[i] = ((unsigned)v < (unsigned)NB) ? v : -1;
        }
        __syncthreads();

        const int ng = (cnt + 31) >> 5;
        int g = wv;
        if (g < ng) pf(g);
        while (g < ng) {
            short8 a0[4], a1[4];
#pragma unroll
            for (int k = 0; k < 4; ++k) {
                a0[k] = pack_frag(bufA[2 * k], bufA[2 * k + 1]);
                a1[k] = pack_frag(bufB[2 * k], bufB[2 * k + 1]);
            }
            const int gn = g + 8;
            if (gn < ng) pf(gn);

            f32x4 acc0[8], acc1[8];
#pragma unroll
            for (int nt = 0; nt < 8; ++nt) { acc0[nt] = (f32x4)(0.0f); acc1[nt] = (f32x4)(0.0f); }

#pragma unroll
            for (int k = 0; k < 4; ++k) {
#pragma unroll
                for (int nt = 0; nt < 8; ++nt) {
                    const short8 b = *(const short8*)(sW1 + (nt * 16 + lr) * LDW + k * 32 + lhi * 8);
                    acc0[nt] = __builtin_amdgcn_mfma_f32_16x16x32_bf16(a0[k], b, acc0[nt], 0, 0, 0);
                    acc1[nt] = __builtin_amdgcn_mfma_f32_16x16x32_bf16(a1[k], b, acc1[nt], 0, 0, 0);
                }
            }

#pragma unroll
            for (int nt = 0; nt < 8; ++nt)
#pragma unroll
                for (int r = 0; r < 4; ++r) {
                    hs[(lhi * 4 + r) * LDH + nt * 16 + lr]      = __float2bfloat16(acc0[nt][r] + cb[nt]);
                    hs[(16 + lhi * 4 + r) * LDH + nt * 16 + lr] = __float2bfloat16(acc1[nt][r] + cb[nt]);
                }

#pragma unroll
            for (int nt = 0; nt < 8; ++nt) { acc0[nt] = (f32x4)(0.0f); acc1[nt] = (f32x4)(0.0f); }

#pragma unroll
            for (int k = 0; k < 4; ++k) {
                const short8 ah0 = *(const short8*)(hs + lr * LDH + k * 32 + lhi * 8);
                const short8 ah1 = *(const short8*)(hs + (16 + lr) * LDH + k * 32 + lhi * 8);
#pragma unroll
                for (int nt = 0; nt < 8; ++nt) {
                    const short8 b = *(const short8*)(sW2 + (nt * 16 + lr) * LDW + k * 32 + lhi * 8);
                    acc0[nt] = __builtin_amdgcn_mfma_f32_16x16x32_bf16(ah0, b, acc0[nt], 0, 0, 0);
                    acc1[nt] = __builtin_amdgcn_mfma_f32_16x16x32_bf16(ah1, b, acc1[nt], 0, 0, 0);
                }
            }

            {
                int g0[4], g1[4];
#pragma unroll
                for (int r = 0; r < 4; ++r) {
                    g0[r] = sRowLds[(g << 5) + lhi * 4 + r];
                    g1[r] = sRowLds[(g << 5) + 16 + lhi * 4 + r];
                }
#pragma unroll
                for (int nt = 0; nt < 8; ++nt)
#pragma unroll
                    for (int r = 0; r < 4; ++r) {
                        if (g0[r] >= 0)
                            out[(long)g0[r] * 128 + nt * 16 + lr] = acc0[nt][r] + db[nt];
                        if (g1[r] >= 0)
                            out[(long)g1[r] * 128 + nt * 16 + lr] = acc1[nt][r] + db[nt];
                    }
            }
            g = gn;
        }
    }
}

// ------------------------------------------------------------- k_fallback ---
__global__ __launch_bounds__(256)
void k_fallback(const float* __restrict__ z,
                const int* __restrict__ si, const int* __restrict__ ti,
                const float* __restrict__ ew,
                const float* __restrict__ dw,
                const float* __restrict__ cp,
                const float* __restrict__ dp,
                float* __restrict__ out) {
    __shared__ float sh[4][128];
    const int lane = threadIdx.x & 63, wv = threadIdx.x >> 6;
    for (int row = blockIdx.x * 4 + wv; row < NB; row += (int)gridDim.x * 4) {
        const int sc = si[row] & (NCH - 1), tc = ti[row] & (NCH - 1);
        const float* zr = z + (long)row * 128;
        const float* W1 = ew + sc * 16384;
        float h0 = cp[sc * 128 + lane];
        float h1 = cp[sc * 128 + lane + 64];
        for (int d = 0; d < 128; ++d) {
            const float zv = zr[d];
            h0 += zv * W1[lane * 128 + d];
            h1 += zv * W1[(lane + 64) * 128 + d];
        }
        sh[wv][lane] = h0;
        sh[wv][lane + 64] = h1;
        __syncthreads();
        const float* W2 = dw + tc * 16384;
        float o0 = dp[tc * 128 + lane];
        float o1 = dp[tc * 128 + lane + 64];
        for (int r = 0; r < 128; ++r) {
            const float hv = sh[wv][r];
            o0 += hv * W2[lane * 128 + r];
            o1 += hv * W2[(lane + 64) * 128 + r];
        }
        out[(long)row * 128 + lane] = o0;
        out[(long)row * 128 + lane + 64] = o1;
        __syncthreads();
    }
}

// ----------------------------------------------------------------- launch ---
extern "C" void kernel_launch(void* const* d_in, const int* in_sizes, int n_in,
                              void* d_out, int out_size, void* d_ws, size_t ws_size,
                              hipStream_t stream) {
    // Reference dtypes: all float tensors float32, indices int32, output float32.
    const float* z  = (const float*)d_in[0];
    const int*   si = (const int*)d_in[1];
    const int*   ti = (const int*)d_in[2];
    const float* ew = (const float*)d_in[3];
    const float* dw = (const float*)d_in[4];
    const float* cp = (const float*)d_in[5];
    const float* dp = (const float*)d_in[6];
    float* out = (float*)d_out;

    if (ws_size >= (size_t)WS_FULL) {
        int*   hist   = (int*)d_ws + WS_HIST;    // 256, becomes cursor after scan
        int*   off    = (int*)d_ws + WS_OFF;     // 257
        int*   sorted = (int*)d_ws + WS_SORTED;  // NB
        short* wbf    = (short*)((int*)d_ws + WS_WBF);   // 1MB bf16 weight image

        (void)hipMemsetAsync(hist, 0, NPAIR * sizeof(int), stream);
        k_pre<<<192, 256, 0, stream>>>(si, ti, hist, ew, dw, wbf);
        k_scan<<<1, NPAIR, 0, stream>>>(hist, off);
        k_scatter<<<128, 256, 0, stream>>>(si, ti, hist, sorted);
        k_gemm2<<<512, 256, 0, stream>>>(z, wbf, cp, dp, off, sorted, out);
    } else if (ws_size >= (size_t)WS_BYTES) {
        int* hist   = (int*)d_ws + WS_HIST;
        int* off    = (int*)d_ws + WS_OFF;
        int* sorted = (int*)d_ws + WS_SORTED;

        k_init<<<1, NPAIR, 0, stream>>>(hist);
        k_hist<<<128, 256, 0, stream>>>(si, ti, hist);
        k_scan<<<1, NPAIR, 0, stream>>>(hist, off);
        k_scatter<<<128, 256, 0, stream>>>(si, ti, hist, sorted);
        k_gemm<<<NPAIR, 512, 0, stream>>>(z, ew, dw, cp, dp, off, sorted, out);
    } else {
        k_fallback<<<1024, 256, 0, stream>>>(z, si, ti, ew, dw, cp, dp, out);
    }
}